// Round 4
// baseline (22.256 us; speedup 1.0000x reference)
//
#include <hip/hip_runtime.h>

// constant_current_lif_encode, bit-exact vs float32 reference:
//   v <- v + 0.1f*((0 - v) + I)   ; each op individually rounded, NO fma
//   z <- (v > 1.0f)               ; exact heaviside(v-1) by Sterbenz
//   v <- 0 on spike               ; exact (v - 1*(v-0) = 0)
//
// Round 4: float4 stores x 4-way time split.
//   thread (i4, q): i4 in [0, n/4) float4-group, q in [0,4) owns t in [25q, 25q+25)
//   -> 262144 threads = 16 waves/CU, 25 dwordx4 stores per thread (1 KB/wave-instr,
//      same store profile as the 6.8 TB/s fill kernel), 4 staggered store streams.
//   q is block-uniform (n/4 = 65536 = 256 blocks per quarter) -> no divergence.
//   Replay of first 25q steps is pure VALU, hidden under other quarters' stores.
//
// Exactness: reset hits exactly 0.0f, and the replay performs the identical
// individually-rounded op sequence (_rn intrinsics forbid FMA contraction),
// so each quarter's starting v is bit-identical to the continuous trajectory.

#define QSTEPS 25

__global__ __launch_bounds__(256)
void ConstantCurrentLIFEncoder_10436770530031_kernel(
    const float* __restrict__ in, float* __restrict__ out, int n4)
{
    const int tid = blockIdx.x * blockDim.x + threadIdx.x;
    const int i = tid & (n4 - 1);     // float4-group index (n4 = 65536, power of two)
    const int q = tid >> 16;          // time quarter 0..3 (tid / n4)

    const float4 I = reinterpret_cast<const float4*>(in)[i];
    float4* __restrict__ out4 = reinterpret_cast<float4*>(out);

    float v0 = 0.0f, v1 = 0.0f, v2 = 0.0f, v3 = 0.0f;

    // Replay quarters [0, q) without stores — bit-identical trajectory.
    for (int tq = 0; tq < q; ++tq) {
        #pragma unroll
        for (int t = 0; t < QSTEPS; ++t) {
            v0 = __fadd_rn(v0, __fmul_rn(0.1f, __fsub_rn(I.x, v0)));
            v1 = __fadd_rn(v1, __fmul_rn(0.1f, __fsub_rn(I.y, v1)));
            v2 = __fadd_rn(v2, __fmul_rn(0.1f, __fsub_rn(I.z, v2)));
            v3 = __fadd_rn(v3, __fmul_rn(0.1f, __fsub_rn(I.w, v3)));
            if (v0 > 1.0f) v0 = 0.0f;
            if (v1 > 1.0f) v1 = 0.0f;
            if (v2 > 1.0f) v2 = 0.0f;
            if (v3 > 1.0f) v3 = 0.0f;
        }
    }

    // Own quarter: simulate + store t = 25q .. 25q+24.
    float4* __restrict__ o = out4 + (size_t)q * QSTEPS * (size_t)n4 + (size_t)i;

    #pragma unroll
    for (int t = 0; t < QSTEPS; ++t) {
        v0 = __fadd_rn(v0, __fmul_rn(0.1f, __fsub_rn(I.x, v0)));
        v1 = __fadd_rn(v1, __fmul_rn(0.1f, __fsub_rn(I.y, v1)));
        v2 = __fadd_rn(v2, __fmul_rn(0.1f, __fsub_rn(I.z, v2)));
        v3 = __fadd_rn(v3, __fmul_rn(0.1f, __fsub_rn(I.w, v3)));

        float4 z;
        z.x = (v0 > 1.0f) ? 1.0f : 0.0f;
        z.y = (v1 > 1.0f) ? 1.0f : 0.0f;
        z.z = (v2 > 1.0f) ? 1.0f : 0.0f;
        z.w = (v3 > 1.0f) ? 1.0f : 0.0f;
        o[(size_t)t * (size_t)n4] = z;

        if (z.x != 0.0f) v0 = 0.0f;
        if (z.y != 0.0f) v1 = 0.0f;
        if (z.z != 0.0f) v2 = 0.0f;
        if (z.w != 0.0f) v3 = 0.0f;
    }
}

extern "C" void kernel_launch(void* const* d_in, const int* in_sizes, int n_in,
                              void* d_out, int out_size, void* d_ws, size_t ws_size,
                              hipStream_t stream) {
    const float* in = (const float*)d_in[0];
    float* out = (float*)d_out;
    const int n = in_sizes[0];          // 262144
    const int n4 = n / 4;               // 65536 = 2^16
    const int block = 256;
    const int grid = (4 * n4) / block;  // 1024 blocks -> 16 waves/CU
    ConstantCurrentLIFEncoder_10436770530031_kernel<<<grid, block, 0, stream>>>(in, out, n4);
}